// Round 1
// baseline (579.592 us; speedup 1.0000x reference)
//
#include <hip/hip_runtime.h>

typedef unsigned short u16;
typedef unsigned int   u32;
typedef __attribute__((ext_vector_type(4))) float f32x4;
typedef __attribute__((ext_vector_type(8))) short s16x8;
typedef __attribute__((ext_vector_type(4))) u32   u32x4;
typedef __attribute__((ext_vector_type(4))) u16   u16x4;

#define DEV static __device__ __forceinline__

DEV float bf2f(u16 a) { union { u32 u; float f; } x; x.u = ((u32)a) << 16; return x.f; }
DEV u16 f2bf(float f) {
  union { float f; u32 u; } x; x.f = f;
  u32 r = (x.u + 0x7FFFu + ((x.u >> 16) & 1u)) >> 16;
  return (u16)r;
}
DEV float wsum(float v) {
#pragma unroll
  for (int m = 32; m; m >>= 1) v += __shfl_xor(v, m, 64);
  return v;
}

// ---------------- constants ----------------
// DIM=192, RES=(8,56,56), HEADS=6, hd=32, WS=(2,7,7), SS=(1,3,3)
// B=2, L=25088, windows per batch 4*8*8=256, Bn=512, N=98, M=50176 token rows

// ---------------- kernel 1: LN1 + shift + window partition ----------------
__global__ __launch_bounds__(256) void k_ln1_win(
    const float* __restrict__ x, const float* __restrict__ g, const float* __restrict__ b,
    u16* __restrict__ xw)
{
  int row  = blockIdx.x * 4 + (threadIdx.x >> 6);
  int lane = threadIdx.x & 63;
  int win = row / 98, tok = row - win * 98;
  int bb = win >> 8, wrem = win & 255;
  int wd = wrem >> 6, wh = (wrem >> 3) & 7, ww = wrem & 7;
  int td = tok >= 49; int tr = tok - td * 49; int th = tr / 7, tw = tr - th * 7;
  int dsrc = (wd * 2 + td + 1) & 7;
  int hs = wh * 7 + th + 3; if (hs >= 56) hs -= 56;
  int wsc = ww * 7 + tw + 3; if (wsc >= 56) wsc -= 56;
  const float* xr = x + ((size_t)bb * 25088 + (size_t)dsrc * 3136 + hs * 56 + wsc) * 192;
  float v0 = xr[lane], v1 = xr[lane + 64], v2 = xr[lane + 128];
  float mu  = wsum(v0 + v1 + v2) * (1.f / 192.f);
  float sq  = wsum(v0 * v0 + v1 * v1 + v2 * v2) * (1.f / 192.f);
  float inv = rsqrtf(sq - mu * mu + 1e-5f);
  u16* orow = xw + (size_t)row * 192;
  orow[lane      ] = f2bf((v0 - mu) * inv * g[lane      ] + b[lane      ]);
  orow[lane + 64 ] = f2bf((v1 - mu) * inv * g[lane + 64 ] + b[lane + 64 ]);
  orow[lane + 128] = f2bf((v2 - mu) * inv * g[lane + 128] + b[lane + 128]);
}

// ---------------- kernel 4: window reverse + residual + LN2 ----------------
__global__ __launch_bounds__(256) void k_merge_ln2(
    const float* __restrict__ x, const u16* __restrict__ ao,
    const float* __restrict__ g, const float* __restrict__ b,
    float* __restrict__ x2, u16* __restrict__ xn2)
{
  int m = blockIdx.x * 4 + (threadIdx.x >> 6);
  int lane = threadIdx.x & 63;
  int bb = m / 25088, l = m - bb * 25088;
  int d = l / 3136; int rem = l - d * 3136; int h = rem / 56, w = rem - h * 56;
  int dsh = (d + 7) & 7;
  int hsh = h - 3; if (hsh < 0) hsh += 56;
  int wsh = w - 3; if (wsh < 0) wsh += 56;
  int wd = dsh >> 1, td = dsh & 1;
  int wh = hsh / 7, th = hsh - wh * 7;
  int ww = wsh / 7, tw = wsh - ww * 7;
  int win = (bb << 8) + (wd << 6) + (wh << 3) + ww;
  int tok = td * 49 + th * 7 + tw;
  const u16* ar = ao + ((size_t)win * 98 + tok) * 192;
  const float* xr = x + (size_t)m * 192;
  float v0 = xr[lane      ] + bf2f(ar[lane      ]);
  float v1 = xr[lane + 64 ] + bf2f(ar[lane + 64 ]);
  float v2 = xr[lane + 128] + bf2f(ar[lane + 128]);
  float* x2r = x2 + (size_t)m * 192;
  x2r[lane] = v0; x2r[lane + 64] = v1; x2r[lane + 128] = v2;
  float mu  = wsum(v0 + v1 + v2) * (1.f / 192.f);
  float sq  = wsum(v0 * v0 + v1 * v1 + v2 * v2) * (1.f / 192.f);
  float inv = rsqrtf(sq - mu * mu + 1e-5f);
  u16* nr = xn2 + (size_t)m * 192;
  nr[lane      ] = f2bf((v0 - mu) * inv * g[lane      ] + b[lane      ]);
  nr[lane + 64 ] = f2bf((v1 - mu) * inv * g[lane + 64 ] + b[lane + 64 ]);
  nr[lane + 128] = f2bf((v2 - mu) * inv * g[lane + 128] + b[lane + 128]);
}

// ---------------- MFMA GEMM: C[M][N] = A[M][K](bf16) @ W[N][K](fp32->bf16)^T ----------------
// EPI 0: +bias, scatter qkv   EPI 1: +bias, relu -> bf16   EPI 2: +bias, relu, +x2 -> fp32
template<int EPI, int KTOT, int NTOT>
__global__ __launch_bounds__(256) void k_gemm(
    const u16* __restrict__ A, const float* __restrict__ W, const float* __restrict__ bias,
    u16* __restrict__ oq, u16* __restrict__ ok, u16* __restrict__ ov,
    const float* __restrict__ x2, float* __restrict__ of)
{
  constexpr int NT = NTOT / 64;
  int mb = blockIdx.x / NT, nb = blockIdx.x - mb * NT;
  int m0 = mb * 64, n0 = nb * 64;
  __shared__ u16 As[64][200];
  __shared__ u16 Ws[64][200];
  int tid = threadIdx.x, lane = tid & 63, wv = tid >> 6;
  int wm = wv >> 1, wn = wv & 1, lr = lane & 15, lg = lane >> 4;
  f32x4 acc[2][2] = {{{0.f,0.f,0.f,0.f},{0.f,0.f,0.f,0.f}},
                     {{0.f,0.f,0.f,0.f},{0.f,0.f,0.f,0.f}}};
  for (int kc = 0; kc < KTOT; kc += 192) {
    // stage A: 64 x 192 bf16 (16B units)
    for (int u = tid; u < 1536; u += 256) {
      int r = u / 24, c = u - r * 24;
      *reinterpret_cast<u32x4*>(&As[r][c * 8]) =
        *reinterpret_cast<const u32x4*>(&A[(size_t)(m0 + r) * KTOT + kc + c * 8]);
    }
    // stage W: 64 x 192 fp32 -> bf16
    for (int u = tid; u < 3072; u += 256) {
      int r = u / 48, c = u - r * 48;
      f32x4 w4 = *reinterpret_cast<const f32x4*>(&W[(size_t)(n0 + r) * KTOT + kc + c * 4]);
      u16x4 o; o[0] = f2bf(w4[0]); o[1] = f2bf(w4[1]); o[2] = f2bf(w4[2]); o[3] = f2bf(w4[3]);
      *reinterpret_cast<u16x4*>(&Ws[r][c * 4]) = o;
    }
    __syncthreads();
#pragma unroll
    for (int ks = 0; ks < 6; ++ks) {
      s16x8 a0 = *reinterpret_cast<const s16x8*>(&As[wm * 32 +      lr][ks * 32 + lg * 8]);
      s16x8 a1 = *reinterpret_cast<const s16x8*>(&As[wm * 32 + 16 + lr][ks * 32 + lg * 8]);
      s16x8 b0 = *reinterpret_cast<const s16x8*>(&Ws[wn * 32 +      lr][ks * 32 + lg * 8]);
      s16x8 b1 = *reinterpret_cast<const s16x8*>(&Ws[wn * 32 + 16 + lr][ks * 32 + lg * 8]);
      acc[0][0] = __builtin_amdgcn_mfma_f32_16x16x32_bf16(a0, b0, acc[0][0], 0, 0, 0);
      acc[0][1] = __builtin_amdgcn_mfma_f32_16x16x32_bf16(a0, b1, acc[0][1], 0, 0, 0);
      acc[1][0] = __builtin_amdgcn_mfma_f32_16x16x32_bf16(a1, b0, acc[1][0], 0, 0, 0);
      acc[1][1] = __builtin_amdgcn_mfma_f32_16x16x32_bf16(a1, b1, acc[1][1], 0, 0, 0);
    }
    __syncthreads();
  }
#pragma unroll
  for (int mi = 0; mi < 2; ++mi)
#pragma unroll
    for (int ni = 0; ni < 2; ++ni)
#pragma unroll
      for (int r = 0; r < 4; ++r) {
        int m = m0 + wm * 32 + mi * 16 + lg * 4 + r;
        int n = n0 + wn * 32 + ni * 16 + lr;
        float val = acc[mi][ni][r] + bias[n];
        if constexpr (EPI == 0) {
          int head = n / 96; int nr2 = n - head * 96; int dd = nr2 / 3; int t = nr2 - dd * 3;
          int win = m / 98; int tok = m - win * 98;
          size_t dst = (((size_t)win * 6 + head) * 98 + tok) * 32 + dd;
          u16 bv = f2bf(val);
          if (t == 0) oq[dst] = bv; else if (t == 1) ok[dst] = bv; else ov[dst] = bv;
        } else if constexpr (EPI == 1) {
          oq[(size_t)m * NTOT + n] = f2bf(fmaxf(val, 0.f));
        } else {
          size_t idx = (size_t)m * NTOT + n;
          of[idx] = fmaxf(val, 0.f) + x2[idx];
        }
      }
}

// ---------------- kernel 3: windowed attention ----------------
__global__ __launch_bounds__(256) void k_attn(
    const u16* __restrict__ qg, const u16* __restrict__ kg, const u16* __restrict__ vg,
    const float* __restrict__ relt, u16* __restrict__ ao)
{
  __shared__ float Ks[98][32];
  __shared__ float Vs[98][32];
  __shared__ float S[98][98];
  __shared__ float rs[98];
  __shared__ int   cnt[98];
  int bid = blockIdx.x;
  int win = bid / 6, head = bid - win * 6;
  int tid = threadIdx.x;
  int base = (win * 6 + head) * 98 * 32;
  for (int i = tid; i < 98 * 32; i += 256) {
    Ks[i >> 5][i & 31] = bf2f(kg[base + i]);
    Vs[i >> 5][i & 31] = bf2f(vg[base + i]);
  }
  if (tid < 98) {
    int t = tid;
    int td = t >= 49, tr = t - td * 49, th = tr / 7, tw = tr - th * 7;
    int wrem = win & 255;
    int dxs = ((wrem >> 6) << 1) + td;
    int hxs = ((wrem >> 3) & 7) * 7 + th;
    int wxs = (wrem & 7) * 7 + tw;
    int rd = (dxs >= 6) + (dxs >= 7);
    int rh = (hxs >= 49) + (hxs >= 53);
    int rw = (wxs >= 49) + (wxs >= 53);
    cnt[t] = rd * 9 + rh * 3 + rw;
  }
  __syncthreads();
  if (tid < 196) {
    int t = tid >> 1, jh = tid & 1;
    const float sc = 0.17677669529663687f;  // 32^-0.5
    f32x4 qr[8];
    const u16* qp = qg + base + t * 32;
#pragma unroll
    for (int i = 0; i < 8; ++i) {
      qr[i][0] = bf2f(qp[i * 4 + 0]) * sc;
      qr[i][1] = bf2f(qp[i * 4 + 1]) * sc;
      qr[i][2] = bf2f(qp[i * 4 + 2]) * sc;
      qr[i][3] = bf2f(qp[i * 4 + 3]) * sc;
    }
    int td = t >= 49, tr = t - td * 49, th = tr / 7, tw = tr - th * 7;
    int ct = cnt[t];
    for (int jj = 0; jj < 49; ++jj) {
      int j = jh * 49 + jj;
      const f32x4* kp = reinterpret_cast<const f32x4*>(Ks[j]);
      float dot = 0.f;
#pragma unroll
      for (int i = 0; i < 8; ++i) {
        f32x4 kv = kp[i];
        dot += qr[i][0] * kv[0] + qr[i][1] * kv[1] + qr[i][2] * kv[2] + qr[i][3] * kv[3];
      }
      int jt = jj / 7, jw = jj - jt * 7;   // jd == jh since j<98
      int ridx = (td - jh + 1) * 169 + (th - jt + 6) * 13 + (tw - jw + 6);
      float bias = relt[ridx * 6 + head];
      float mterm = (ct == cnt[j]) ? 0.f : -100.f;
      S[t][j] = dot + bias + mterm;
    }
  }
  __syncthreads();
  if (tid < 98) {
    int t = tid;
    float mx = -1e30f;
    for (int j = 0; j < 98; ++j) mx = fmaxf(mx, S[t][j]);
    float sum = 0.f;
    for (int j = 0; j < 98; ++j) { float p = __expf(S[t][j] - mx); S[t][j] = p; sum += p; }
    rs[t] = 1.f / sum;
  }
  __syncthreads();
  for (int u = tid; u < 98 * 8; u += 256) {
    int t = u >> 3, dq = u & 7;
    f32x4 acc = {0.f, 0.f, 0.f, 0.f};
    for (int j = 0; j < 98; ++j) {
      float s = S[t][j];
      f32x4 vv = *reinterpret_cast<const f32x4*>(&Vs[j][dq * 4]);
      acc[0] += s * vv[0]; acc[1] += s * vv[1]; acc[2] += s * vv[2]; acc[3] += s * vv[3];
    }
    float r = rs[t];
    size_t ob = ((size_t)win * 98 + t) * 192 + head * 32 + dq * 4;
    ao[ob + 0] = f2bf(acc[0] * r);
    ao[ob + 1] = f2bf(acc[1] * r);
    ao[ob + 2] = f2bf(acc[2] * r);
    ao[ob + 3] = f2bf(acc[3] * r);
  }
}

extern "C" void kernel_launch(void* const* d_in, const int* in_sizes, int n_in,
                              void* d_out, int out_size, void* d_ws, size_t ws_size,
                              hipStream_t stream) {
  (void)in_sizes; (void)n_in; (void)out_size; (void)ws_size;
  const float* x    = (const float*)d_in[0];
  const float* n1g  = (const float*)d_in[1];
  const float* n1b  = (const float*)d_in[2];
  const float* qkvw = (const float*)d_in[3];
  const float* qkvb = (const float*)d_in[4];
  const float* relt = (const float*)d_in[5];
  const float* n2g  = (const float*)d_in[6];
  const float* n2b  = (const float*)d_in[7];
  const float* w1   = (const float*)d_in[8];
  const float* b1   = (const float*)d_in[9];
  const float* w2   = (const float*)d_in[10];
  const float* b2   = (const float*)d_in[11];
  float* out = (float*)d_out;
  char* ws = (char*)d_ws;

  constexpr size_t SZB = 50176ull * 192 * 2;  // 19,267,584 bytes (one bf16 activation plane)
  u16*  xw  = (u16*)(ws);               // also attn_out (alias, xw dead after QKV)
  u16*  q   = (u16*)(ws + SZB);
  u16*  k   = (u16*)(ws + 2 * SZB);
  u16*  v   = (u16*)(ws + 3 * SZB);
  float* x2 = (float*)(ws + SZB);       // alias q,k (dead after attention)
  u16*  xn2 = (u16*)(ws + 3 * SZB);     // alias v
  u16*  h1  = (u16*)(ws + 4 * SZB);     // 77,070,336 bytes
  u16*  ao  = xw;

  k_ln1_win<<<12544, 256, 0, stream>>>(x, n1g, n1b, xw);
  k_gemm<0, 192, 576><<<784 * 9, 256, 0, stream>>>(xw, qkvw, qkvb, q, k, v, nullptr, nullptr);
  k_attn<<<3072, 256, 0, stream>>>(q, k, v, relt, ao);
  k_merge_ln2<<<12544, 256, 0, stream>>>(x, ao, n2g, n2b, x2, xn2);
  k_gemm<1, 192, 768><<<784 * 12, 256, 0, stream>>>(xn2, w1, b1, h1, nullptr, nullptr, nullptr, nullptr);
  k_gemm<2, 768, 192><<<784 * 3, 256, 0, stream>>>(h1, w2, b2, nullptr, nullptr, nullptr, x2, out);
}

// Round 2
// 376.131 us; speedup vs baseline: 1.5409x; 1.5409x over previous
//
#include <hip/hip_runtime.h>

typedef unsigned short u16;
typedef unsigned int   u32;
typedef __attribute__((ext_vector_type(4))) float f32x4;
typedef __attribute__((ext_vector_type(8))) short s16x8;
typedef __attribute__((ext_vector_type(4))) u32   u32x4;
typedef __attribute__((ext_vector_type(4))) u16   u16x4;

#define DEV static __device__ __forceinline__

DEV float bf2f(u16 a) { union { u32 u; float f; } x; x.u = ((u32)a) << 16; return x.f; }
DEV u16 f2bf(float f) {
  union { float f; u32 u; } x; x.f = f;
  u32 r = (x.u + 0x7FFFu + ((x.u >> 16) & 1u)) >> 16;
  return (u16)r;
}
DEV float wsum(float v) {
#pragma unroll
  for (int m = 32; m; m >>= 1) v += __shfl_xor(v, m, 64);
  return v;
}

// ---------------- constants ----------------
// DIM=192, RES=(8,56,56), HEADS=6, hd=32, WS=(2,7,7), SS=(1,3,3)
// B=2, L=25088, windows per batch 4*8*8=256, Bn=512, N=98, M=50176 token rows

// ---------------- kernel 1: LN1 + shift + window partition ----------------
__global__ __launch_bounds__(256) void k_ln1_win(
    const float* __restrict__ x, const float* __restrict__ g, const float* __restrict__ b,
    u16* __restrict__ xw)
{
  int row  = blockIdx.x * 4 + (threadIdx.x >> 6);
  int lane = threadIdx.x & 63;
  int win = row / 98, tok = row - win * 98;
  int bb = win >> 8, wrem = win & 255;
  int wd = wrem >> 6, wh = (wrem >> 3) & 7, ww = wrem & 7;
  int td = tok >= 49; int tr = tok - td * 49; int th = tr / 7, tw = tr - th * 7;
  int dsrc = (wd * 2 + td + 1) & 7;
  int hs = wh * 7 + th + 3; if (hs >= 56) hs -= 56;
  int wsc = ww * 7 + tw + 3; if (wsc >= 56) wsc -= 56;
  const float* xr = x + ((size_t)bb * 25088 + (size_t)dsrc * 3136 + hs * 56 + wsc) * 192;
  float v0 = xr[lane], v1 = xr[lane + 64], v2 = xr[lane + 128];
  float mu  = wsum(v0 + v1 + v2) * (1.f / 192.f);
  float sq  = wsum(v0 * v0 + v1 * v1 + v2 * v2) * (1.f / 192.f);
  float inv = rsqrtf(sq - mu * mu + 1e-5f);
  u16* orow = xw + (size_t)row * 192;
  orow[lane      ] = f2bf((v0 - mu) * inv * g[lane      ] + b[lane      ]);
  orow[lane + 64 ] = f2bf((v1 - mu) * inv * g[lane + 64 ] + b[lane + 64 ]);
  orow[lane + 128] = f2bf((v2 - mu) * inv * g[lane + 128] + b[lane + 128]);
}

// ---------------- kernel 4: window reverse + residual + LN2 ----------------
__global__ __launch_bounds__(256) void k_merge_ln2(
    const float* __restrict__ x, const u16* __restrict__ ao,
    const float* __restrict__ g, const float* __restrict__ b,
    float* __restrict__ x2, u16* __restrict__ xn2)
{
  int m = blockIdx.x * 4 + (threadIdx.x >> 6);
  int lane = threadIdx.x & 63;
  int bb = m / 25088, l = m - bb * 25088;
  int d = l / 3136; int rem = l - d * 3136; int h = rem / 56, w = rem - h * 56;
  int dsh = (d + 7) & 7;
  int hsh = h - 3; if (hsh < 0) hsh += 56;
  int wsh = w - 3; if (wsh < 0) wsh += 56;
  int wd = dsh >> 1, td = dsh & 1;
  int wh = hsh / 7, th = hsh - wh * 7;
  int ww = wsh / 7, tw = wsh - ww * 7;
  int win = (bb << 8) + (wd << 6) + (wh << 3) + ww;
  int tok = td * 49 + th * 7 + tw;
  const u16* ar = ao + ((size_t)win * 98 + tok) * 192;
  const float* xr = x + (size_t)m * 192;
  float v0 = xr[lane      ] + bf2f(ar[lane      ]);
  float v1 = xr[lane + 64 ] + bf2f(ar[lane + 64 ]);
  float v2 = xr[lane + 128] + bf2f(ar[lane + 128]);
  float* x2r = x2 + (size_t)m * 192;
  x2r[lane] = v0; x2r[lane + 64] = v1; x2r[lane + 128] = v2;
  float mu  = wsum(v0 + v1 + v2) * (1.f / 192.f);
  float sq  = wsum(v0 * v0 + v1 * v1 + v2 * v2) * (1.f / 192.f);
  float inv = rsqrtf(sq - mu * mu + 1e-5f);
  u16* nr = xn2 + (size_t)m * 192;
  nr[lane      ] = f2bf((v0 - mu) * inv * g[lane      ] + b[lane      ]);
  nr[lane + 64 ] = f2bf((v1 - mu) * inv * g[lane + 64 ] + b[lane + 64 ]);
  nr[lane + 128] = f2bf((v2 - mu) * inv * g[lane + 128] + b[lane + 128]);
}

// ---------------- MFMA GEMM: C[M][N] = A[M][K](bf16) @ W[N][K](fp32->bf16)^T ----------------
// EPI 0: +bias, scatter qkv   EPI 1: +bias, relu -> bf16   EPI 2: +bias, relu, +x2 -> fp32
template<int EPI, int KTOT, int NTOT>
__global__ __launch_bounds__(256) void k_gemm(
    const u16* __restrict__ A, const float* __restrict__ W, const float* __restrict__ bias,
    u16* __restrict__ oq, u16* __restrict__ ok, u16* __restrict__ ov,
    const float* __restrict__ x2, float* __restrict__ of)
{
  constexpr int NT = NTOT / 64;
  int mb = blockIdx.x / NT, nb = blockIdx.x - mb * NT;
  int m0 = mb * 64, n0 = nb * 64;
  __shared__ u16 As[64][200];
  __shared__ u16 Ws[64][200];
  int tid = threadIdx.x, lane = tid & 63, wv = tid >> 6;
  int wm = wv >> 1, wn = wv & 1, lr = lane & 15, lg = lane >> 4;
  f32x4 acc[2][2] = {{{0.f,0.f,0.f,0.f},{0.f,0.f,0.f,0.f}},
                     {{0.f,0.f,0.f,0.f},{0.f,0.f,0.f,0.f}}};
  for (int kc = 0; kc < KTOT; kc += 192) {
    // stage A: 64 x 192 bf16 (16B units)
    for (int u = tid; u < 1536; u += 256) {
      int r = u / 24, c = u - r * 24;
      *reinterpret_cast<u32x4*>(&As[r][c * 8]) =
        *reinterpret_cast<const u32x4*>(&A[(size_t)(m0 + r) * KTOT + kc + c * 8]);
    }
    // stage W: 64 x 192 fp32 -> bf16
    for (int u = tid; u < 3072; u += 256) {
      int r = u / 48, c = u - r * 48;
      f32x4 w4 = *reinterpret_cast<const f32x4*>(&W[(size_t)(n0 + r) * KTOT + kc + c * 4]);
      u16x4 o; o[0] = f2bf(w4[0]); o[1] = f2bf(w4[1]); o[2] = f2bf(w4[2]); o[3] = f2bf(w4[3]);
      *reinterpret_cast<u16x4*>(&Ws[r][c * 4]) = o;
    }
    __syncthreads();
#pragma unroll
    for (int ks = 0; ks < 6; ++ks) {
      s16x8 a0 = *reinterpret_cast<const s16x8*>(&As[wm * 32 +      lr][ks * 32 + lg * 8]);
      s16x8 a1 = *reinterpret_cast<const s16x8*>(&As[wm * 32 + 16 + lr][ks * 32 + lg * 8]);
      s16x8 b0 = *reinterpret_cast<const s16x8*>(&Ws[wn * 32 +      lr][ks * 32 + lg * 8]);
      s16x8 b1 = *reinterpret_cast<const s16x8*>(&Ws[wn * 32 + 16 + lr][ks * 32 + lg * 8]);
      acc[0][0] = __builtin_amdgcn_mfma_f32_16x16x32_bf16(a0, b0, acc[0][0], 0, 0, 0);
      acc[0][1] = __builtin_amdgcn_mfma_f32_16x16x32_bf16(a0, b1, acc[0][1], 0, 0, 0);
      acc[1][0] = __builtin_amdgcn_mfma_f32_16x16x32_bf16(a1, b0, acc[1][0], 0, 0, 0);
      acc[1][1] = __builtin_amdgcn_mfma_f32_16x16x32_bf16(a1, b1, acc[1][1], 0, 0, 0);
    }
    __syncthreads();
  }
#pragma unroll
  for (int mi = 0; mi < 2; ++mi)
#pragma unroll
    for (int ni = 0; ni < 2; ++ni)
#pragma unroll
      for (int r = 0; r < 4; ++r) {
        int m = m0 + wm * 32 + mi * 16 + lg * 4 + r;
        int n = n0 + wn * 32 + ni * 16 + lr;
        float val = acc[mi][ni][r] + bias[n];
        if constexpr (EPI == 0) {
          int head = n / 96; int nr2 = n - head * 96; int dd = nr2 / 3; int t = nr2 - dd * 3;
          int win = m / 98; int tok = m - win * 98;
          size_t dst = (((size_t)win * 6 + head) * 98 + tok) * 32 + dd;
          u16 bv = f2bf(val);
          if (t == 0) oq[dst] = bv; else if (t == 1) ok[dst] = bv; else ov[dst] = bv;
        } else if constexpr (EPI == 1) {
          oq[(size_t)m * NTOT + n] = f2bf(fmaxf(val, 0.f));
        } else {
          size_t idx = (size_t)m * NTOT + n;
          of[idx] = fmaxf(val, 0.f) + x2[idx];
        }
      }
}

// ---------------- kernel 3: windowed attention via MFMA ----------------
// block = (win, head); 4 waves; S=Q K^T by 16x16x32 MFMA (K=32=head_dim, 1 MFMA/tile)
// rows padded 98->112 (7 stripes); PV K-dim padded to 128.
__global__ __launch_bounds__(256) void k_attn_mfma(
    const u16* __restrict__ qg, const u16* __restrict__ kg, const u16* __restrict__ vg,
    const float* __restrict__ relt, u16* __restrict__ ao)
{
  __shared__ u16 P[112 * 128];     // unnormalized softmax probs, slot-swizzled
  __shared__ u16 Vt[32 * 136];     // V transposed (d-major), padded stride vs bank conflicts
  __shared__ float relLds[507];
  __shared__ int  code[98];        // (lin<<5)|cnt per token

  int bid = blockIdx.x;
  int win = bid / 6, head = bid - win * 6;
  int tid = threadIdx.x, lane = tid & 63, wv = tid >> 6;
  int lr = lane & 15, lg = lane >> 4;
  size_t base = (size_t)(win * 6 + head) * 98 * 32;

  // zero Vt (padding for PV K-dim 98..127 must be finite/zero)
  for (int u = tid; u < 32 * 136 / 2; u += 256) reinterpret_cast<u32*>(Vt)[u] = 0;
  // stage this head's rel-bias column
  for (int i = tid; i < 507; i += 256) relLds[i] = relt[i * 6 + head];
  // per-token packed codes: lin = td*169+th*13+tw (rel idx), cnt = shift-region id
  if (tid < 98) {
    int t = tid;
    int td = t >= 49, tr = t - td * 49, th = tr / 7, tw = tr - th * 7;
    int wrem = win & 255;
    int dxs = ((wrem >> 6) << 1) + td;
    int hxs = ((wrem >> 3) & 7) * 7 + th;
    int wxs = (wrem & 7) * 7 + tw;
    int rd = (dxs >= 6) + (dxs >= 7);
    int rh = (hxs >= 49) + (hxs >= 53);
    int rw = (wxs >= 49) + (wxs >= 53);
    int cnt = rd * 9 + rh * 3 + rw;
    int lin = td * 169 + th * 13 + tw;
    code[t] = (lin << 5) | cnt;
  }
  __syncthreads();
  // stage V transposed: Vt[d][tok]
  for (int u = tid; u < 98 * 16; u += 256) {
    int tok = u >> 4, dp = (u & 15) * 2;
    u32 w = *reinterpret_cast<const u32*>(&vg[base + tok * 32 + dp]);
    Vt[dp * 136 + tok]       = (u16)(w & 0xFFFFu);
    Vt[(dp + 1) * 136 + tok] = (u16)(w >> 16);
  }
  __syncthreads();

  // K fragments for all 7 col-tiles, held in registers (reused across stripes)
  s16x8 kf[7];
#pragma unroll
  for (int j = 0; j < 7; ++j) {
    int row = j * 16 + lr; if (row > 97) row = 97;
    kf[j] = *reinterpret_cast<const s16x8*>(&kg[base + (size_t)row * 32 + lg * 8]);
  }

  const float sc = 0.17677669529663687f;  // 32^-0.5
  for (int i = wv; i < 7; i += 4) {
    int qrow = i * 16 + lr; if (qrow > 97) qrow = 97;
    s16x8 qf = *reinterpret_cast<const s16x8*>(&qg[base + (size_t)qrow * 32 + lg * 8]);
    f32x4 s[7];
    f32x4 zz = {0.f, 0.f, 0.f, 0.f};
#pragma unroll
    for (int j = 0; j < 7; ++j)
      s[j] = __builtin_amdgcn_mfma_f32_16x16x32_bf16(qf, kf[j], zz, 0, 0, 0);

    int rc[4];
#pragma unroll
    for (int r = 0; r < 4; ++r) {
      int t = i * 16 + lg * 4 + r; if (t > 97) t = 97;
      rc[r] = code[t];
    }
    float mx[4] = {-1e30f, -1e30f, -1e30f, -1e30f};
#pragma unroll
    for (int j = 0; j < 7; ++j) {
      int col = j * 16 + lr;
      bool cv = col < 98;
      int cc = code[cv ? col : 97];
#pragma unroll
      for (int r = 0; r < 4; ++r) {
        float v;
        if (cv) {
          int ridx = (rc[r] >> 5) - (cc >> 5) + 253;
          float bias = relLds[ridx];
          float mterm = (((rc[r] ^ cc) & 31) == 0) ? 0.f : -100.f;
          v = s[j][r] * sc + bias + mterm;
        } else v = -1e30f;
        s[j][r] = v;
        mx[r] = fmaxf(mx[r], v);
      }
    }
#pragma unroll
    for (int m = 1; m < 16; m <<= 1)
#pragma unroll
      for (int r = 0; r < 4; ++r) mx[r] = fmaxf(mx[r], __shfl_xor(mx[r], m, 64));
    float sm[4] = {0.f, 0.f, 0.f, 0.f};
#pragma unroll
    for (int j = 0; j < 7; ++j)
#pragma unroll
      for (int r = 0; r < 4; ++r) {
        float p = __expf(s[j][r] - mx[r]);
        s[j][r] = p;
        sm[r] += p;
      }
#pragma unroll
    for (int m = 1; m < 16; m <<= 1)
#pragma unroll
      for (int r = 0; r < 4; ++r) sm[r] += __shfl_xor(sm[r], m, 64);
    float rinv[4];
#pragma unroll
    for (int r = 0; r < 4; ++r) rinv[r] = 1.f / sm[r];

    // write unnormalized P to LDS (bf16, swizzled: 16B-slot XOR row&7)
#pragma unroll
    for (int j = 0; j < 7; ++j) {
      int col = j * 16 + lr;
      int slot = col >> 3, wi = col & 7;
#pragma unroll
      for (int r = 0; r < 4; ++r) {
        int row = i * 16 + lg * 4 + r;
        P[row * 128 + (((slot ^ (row & 7)) << 3) | wi)] = f2bf(s[j][r]);
      }
    }
    // zero pad cols 112..127 (slots 14,15) for this stripe's rows
    if (lane < 32) {
      int row = i * 16 + lr;
      int slot = 14 + lg;
      u32x4 z4 = {0u, 0u, 0u, 0u};
      *reinterpret_cast<u32x4*>(&P[row * 128 + ((slot ^ (row & 7)) << 3)]) = z4;
    }

    // PV: O[112x32] stripe = P[stripe rows][0..127] @ Vt^T ; only this wave's rows read
    f32x4 o0 = {0.f, 0.f, 0.f, 0.f}, o1 = {0.f, 0.f, 0.f, 0.f};
#pragma unroll
    for (int kc = 0; kc < 4; ++kc) {
      int prow = i * 16 + lr;
      int slot = kc * 4 + lg;
      s16x8 pf = *reinterpret_cast<const s16x8*>(&P[prow * 128 + ((slot ^ (prow & 7)) << 3)]);
      s16x8 vf0 = *reinterpret_cast<const s16x8*>(&Vt[lr * 136 + kc * 32 + lg * 8]);
      s16x8 vf1 = *reinterpret_cast<const s16x8*>(&Vt[(16 + lr) * 136 + kc * 32 + lg * 8]);
      o0 = __builtin_amdgcn_mfma_f32_16x16x32_bf16(pf, vf0, o0, 0, 0, 0);
      o1 = __builtin_amdgcn_mfma_f32_16x16x32_bf16(pf, vf1, o1, 0, 0, 0);
    }
#pragma unroll
    for (int r = 0; r < 4; ++r) {
      int t = i * 16 + lg * 4 + r;
      if (t < 98) {
        size_t ob = ((size_t)win * 98 + t) * 192 + head * 32;
        ao[ob + lr]      = f2bf(o0[r] * rinv[r]);
        ao[ob + 16 + lr] = f2bf(o1[r] * rinv[r]);
      }
    }
  }
}

extern "C" void kernel_launch(void* const* d_in, const int* in_sizes, int n_in,
                              void* d_out, int out_size, void* d_ws, size_t ws_size,
                              hipStream_t stream) {
  (void)in_sizes; (void)n_in; (void)out_size; (void)ws_size;
  const float* x    = (const float*)d_in[0];
  const float* n1g  = (const float*)d_in[1];
  const float* n1b  = (const float*)d_in[2];
  const float* qkvw = (const float*)d_in[3];
  const float* qkvb = (const float*)d_in[4];
  const float* relt = (const float*)d_in[5];
  const float* n2g  = (const float*)d_in[6];
  const float* n2b  = (const float*)d_in[7];
  const float* w1   = (const float*)d_in[8];
  const float* b1   = (const float*)d_in[9];
  const float* w2   = (const float*)d_in[10];
  const float* b2   = (const float*)d_in[11];
  float* out = (float*)d_out;
  char* ws = (char*)d_ws;

  constexpr size_t SZB = 50176ull * 192 * 2;  // 19,267,584 bytes (one bf16 activation plane)
  u16*  xw  = (u16*)(ws);               // also attn_out (alias, xw dead after QKV)
  u16*  q   = (u16*)(ws + SZB);
  u16*  k   = (u16*)(ws + 2 * SZB);
  u16*  v   = (u16*)(ws + 3 * SZB);
  float* x2 = (float*)(ws + SZB);       // alias q,k (dead after attention)
  u16*  xn2 = (u16*)(ws + 3 * SZB);     // alias v
  u16*  h1  = (u16*)(ws + 4 * SZB);     // 77,070,336 bytes
  u16*  ao  = xw;

  k_ln1_win<<<12544, 256, 0, stream>>>(x, n1g, n1b, xw);
  k_gemm<0, 192, 576><<<784 * 9, 256, 0, stream>>>(xw, qkvw, qkvb, q, k, v, nullptr, nullptr);
  k_attn_mfma<<<3072, 256, 0, stream>>>(q, k, v, relt, ao);
  k_merge_ln2<<<12544, 256, 0, stream>>>(x, ao, n2g, n2b, x2, xn2);
  k_gemm<1, 192, 768><<<784 * 12, 256, 0, stream>>>(xn2, w1, b1, h1, nullptr, nullptr, nullptr, nullptr);
  k_gemm<2, 768, 192><<<784 * 3, 256, 0, stream>>>(h1, w2, b2, nullptr, nullptr, nullptr, x2, out);
}